// Round 19
// baseline (242.572 us; speedup 1.0000x reference)
//
#include <hip/hip_runtime.h>
#include <math.h>
#include <stdint.h>

#define BB 64
#define TT 4096
#define WW 64
#define MODES 32
#define NLAYER 4
#define KSPLIT_X 32    // dftx split (grid 32)
#define KSPLIT_TOK 16  // tok split (grid 1024)
#define KSPLIT_L 16    // layer-kernel t-chunk split (1024 blocks)
#define OUTT 4096

typedef uint32_t u32;
typedef __attribute__((ext_vector_type(8))) short bf16x8;
typedef __attribute__((ext_vector_type(16))) float f32x16;

// ws layout (float offsets).  Tables as bf16 hi/lo planes, fragment-major (fm):
//   A-frag:  lane l holds row (l&31)+32*half, k = kbase + (l>>5)*8 + pos
//   B-frag:  lane l holds col (l&31)+32*half, k = kbase + (l>>5)*8 + pos
// hc: SINGLE bf16 plane — h is uniformly bf16 after each layer.
// hc fm (ushort idx): element (b,t,w) at ((b*128+(t>>5))*4+(w>>4))*512 + ((t&31)+32*((w>>3)&1))*8 + (w&7)
#define OFF_HCH  0            // hch fm, 16,777,216 ushort (8,388,608 f)
#define OFF_FTH  16777216     // ftab fm [256 ttile][2 jhalf][64][8] ushort
#define OFF_FTL  16908288
#define OFF_ITH  17039360     // itab fm [128 t32][4 kt][64][8] ushort
#define OFF_ITL  17170432
#define OFF_PWH  17301504     // pw fm [4 layer][2 ohalf][4 kt][64][8] ushort
#define OFF_PWL  17309696
#define OFF_P1H  17317888     // p1 fm [2][4][64][8] ushort
#define OFF_P1L  17319936
#define OFF_YH   17321984     // Y fm [64 b][2 ohalf][4 kt][64][8] ushort
#define OFF_YL   17453056
#define OFF_XFP  17584128     // xfPart [16][64][64][64] f32; dftx partials (pre-L0) + tok partials reuse
#define OFF_XFB  21778432     // xfb [64][64][64] f32
#define OFF_SCH  22040576     // sc hi fm ushort (131072 f)
#define OFF_SCL  22171648     // sc lo fm
#define OFF_PWLW 22302720     // [64]
#define OFF_PWLB 22302784     // [64]
#define OFF_XFXP 22302848     // sincos LUT (8192 f)
#define OFF_XFXT 22335616     // [64][64] f32

// fast exact-form GELU: branch-free A&S 7.1.26 erf, |err(erf)| <= 1.5e-7
__device__ __forceinline__ float gelu_exact(float x) {
    float ax = fabsf(x);
    float z  = ax * 0.70710678118654752f;
    float t  = __builtin_amdgcn_rcpf(fmaf(0.3275911f, z, 1.0f));
    float ex = __builtin_amdgcn_exp2f(z * z * -1.44269504088896341f);
    float p  = fmaf(fmaf(fmaf(fmaf(1.061405429f, t, -1.453152027f),
                              t, 1.421413741f), t, -0.284496736f), t, 0.254829592f);
    float er = 1.0f - p * t * ex;
    er = copysignf(er, x);
    return 0.5f * x * (1.0f + er);
}
__device__ __forceinline__ u32 bfrn(float f) {
    u32 u = __float_as_uint(f);
    return (u + 0x7fffu + ((u >> 16) & 1u)) >> 16;
}
__device__ __forceinline__ void packf2(float f, ushort& hi, ushort& lo) {
    u32 h = bfrn(f);
    float r = f - __uint_as_float(h << 16);
    hi = (ushort)h;
    lo = (ushort)bfrn(r);
}
__device__ __forceinline__ u32 packf(float f) {
    ushort h, l; packf2(f, h, l);
    return (u32)h | ((u32)l << 16);
}
__device__ __forceinline__ void cvt8(const float* f, bf16x8& hi, bf16x8& lo) {
    union { bf16x8 v; ushort u[8]; } H, L;
    #pragma unroll
    for (int i = 0; i < 8; ++i) {
        ushort h, l; packf2(f[i], h, l);
        H.u[i] = h; L.u[i] = l;
    }
    hi = H.v; lo = L.v;
}

#define MM3(ah, al, bh, bl, acc)                                          \
    acc = __builtin_amdgcn_mfma_f32_32x32x16_bf16(ah, bh, acc, 0, 0, 0);  \
    acc = __builtin_amdgcn_mfma_f32_32x32x16_bf16(ah, bl, acc, 0, 0, 0);  \
    acc = __builtin_amdgcn_mfma_f32_32x32x16_bf16(al, bh, acc, 0, 0, 0);

#define MM3_EVEN(ah, al, bh, bl, accA, accB)                                \
    accA = __builtin_amdgcn_mfma_f32_32x32x16_bf16(ah, bh, accA, 0, 0, 0);  \
    accB = __builtin_amdgcn_mfma_f32_32x32x16_bf16(ah, bl, accB, 0, 0, 0);  \
    accA = __builtin_amdgcn_mfma_f32_32x32x16_bf16(al, bh, accA, 0, 0, 0);
#define MM3_ODD(ah, al, bh, bl, accA, accB)                                 \
    accB = __builtin_amdgcn_mfma_f32_32x32x16_bf16(ah, bh, accB, 0, 0, 0);  \
    accA = __builtin_amdgcn_mfma_f32_32x32x16_bf16(ah, bl, accA, 0, 0, 0);  \
    accB = __builtin_amdgcn_mfma_f32_32x32x16_bf16(al, bh, accB, 0, 0, 0);
#define MM2(ah, al, bh, accA, accB)                                         \
    accA = __builtin_amdgcn_mfma_f32_32x32x16_bf16(ah, bh, accA, 0, 0, 0);  \
    accB = __builtin_amdgcn_mfma_f32_32x32x16_bf16(al, bh, accB, 0, 0, 0);

#define ACC_ZERO(acc) { _Pragma("unroll") for (int _i = 0; _i < 16; ++_i) acc[_i] = 0.0f; }

// ---------------- sincos LUT ----------------
__global__ __launch_bounds__(256) void sincos_lut_kernel(float* __restrict__ lut) {
    int a = blockIdx.x * 256 + threadIdx.x;    // 0..4095
    const float w0 = 6.28318530717958647692f / (float)TT;
    float s, c; sincosf((float)a * w0, &s, &c);
    lut[a * 2]     = c;
    lut[a * 2 + 1] = s;
}

// ---------------- tables (fragment-major, from LUT) ----------------
__global__ __launch_bounds__(256) void build_tables_kernel(const float* __restrict__ lut,
                                                           ushort* __restrict__ fth, ushort* __restrict__ ftl,
                                                           ushort* __restrict__ ith, ushort* __restrict__ itl) {
    const int idx = blockIdx.x * 256 + threadIdx.x;   // 0..262143
    {   // ftab fm: A-frag rows j, k=t.
        int pos = idx & 7, l = (idx >> 3) & 63, half = (idx >> 9) & 1, ttile = idx >> 10;
        int j = half * 32 + (l & 31);
        int t = ttile * 16 + (l >> 5) * 8 + pos;
        int m = j & 31;
        int a = (m * t) & (TT - 1);
        float c = lut[a * 2], s = lut[a * 2 + 1];
        u32 p = packf((j < 32) ? c : -s);
        fth[idx] = (ushort)(p & 0xffffu); ftl[idx] = (ushort)(p >> 16);
    }
    {   // itab fm: B-frag cols t, k=j.
        int pos = idx & 7, l = (idx >> 3) & 63, kt = (idx >> 9) & 3, t32 = idx >> 11;
        int t = t32 * 32 + (l & 31);
        int j = kt * 16 + (l >> 5) * 8 + pos;
        int m = j & 31;
        int a = (m * t) & (TT - 1);
        float c = lut[a * 2], s = lut[a * 2 + 1];
        float v;
        if (j == 0)       v = 1.0f / (float)TT;
        else if (j < 32)  v = (2.0f / (float)TT) * c;
        else if (j == 32) v = 0.0f;
        else              v = -(2.0f / (float)TT) * s;
        u32 p = packf(v);
        ith[idx] = (ushort)(p & 0xffffu); itl[idx] = (ushort)(p >> 16);
    }
}

// ---------------- weights: fm planes + layer-0 rank-1 folds ----------------
__global__ __launch_bounds__(256) void wconv_kernel(const float* __restrict__ pww, const float* __restrict__ p1w,
                                                    const float* __restrict__ lw, const float* __restrict__ lb,
                                                    const float* __restrict__ pwb,
                                                    ushort* __restrict__ pwh, ushort* __restrict__ pwl,
                                                    ushort* __restrict__ p1h, ushort* __restrict__ p1l,
                                                    float* __restrict__ pwlw, float* __restrict__ pwlb) {
    int idx = blockIdx.x * 256 + threadIdx.x;
    if (idx < NLAYER * 4096) {
        int pos = idx & 7, l = (idx >> 3) & 63, kt = (idx >> 9) & 3, half = (idx >> 11) & 1, layer = idx >> 12;
        int o = half * 32 + (l & 31);
        int w = kt * 16 + (l >> 5) * 8 + pos;
        u32 p = packf(pww[layer * 4096 + o * 64 + w]);
        pwh[idx] = (ushort)(p & 0xffffu); pwl[idx] = (ushort)(p >> 16);
    } else if (idx < NLAYER * 4096 + 4096) {
        int k = idx - NLAYER * 4096;
        int pos = k & 7, l = (k >> 3) & 63, kt = (k >> 9) & 3, half = (k >> 11) & 1;
        int wp = half * 32 + (l & 31);
        int w = kt * 16 + (l >> 5) * 8 + pos;
        u32 p = packf(p1w[wp * 64 + w]);
        p1h[k] = (ushort)(p & 0xffffu); p1l[k] = (ushort)(p >> 16);
    } else if (idx < NLAYER * 4096 + 4096 + 64) {
        int o = idx - (NLAYER * 4096 + 4096);
        float aw = 0.f, ab = 0.f;
        for (int w = 0; w < 64; ++w) {
            float pv = pww[o * 64 + w];   // layer 0
            aw += pv * lw[w];
            ab += pv * lb[w];
        }
        pwlw[o] = aw;
        pwlb[o] = ab + pwb[o];
    }
}

// Y fm write helper
__device__ __forceinline__ size_t yfm_idx(int b, int o, int j) {
    return ((((size_t)b * 2 + (o >> 5)) * 4 + (j >> 4)) * 64 + (o & 31) + 32 * ((j >> 3) & 1)) * 8 + (j & 7);
}

// ---------------- dftx ----------------
__global__ __launch_bounds__(256) void dftx_kernel(const float* __restrict__ x,
                                                   const ushort* __restrict__ fth,
                                                   const ushort* __restrict__ ftl,
                                                   float* __restrict__ xfxp) {
    const int kc = blockIdx.x;
    const int tid = threadIdx.x, l = tid & 63, q = tid >> 6;
    const int mt = q >> 1, nt = q & 1;
    const int bc = nt * 32 + (l & 31);
    const int kh = (l >> 5) * 8;
    f32x16 acc; ACC_ZERO(acc);
    for (int ks = 0; ks < 4096 / KSPLIT_X / 16; ++ks) {
        int k0 = kc * (4096 / KSPLIT_X) + ks * 16 + kh;
        size_t fo = (((size_t)(kc * (4096 / KSPLIT_X / 16) + ks) * 2 + mt) * 64 + l) * 8;
        bf16x8 ah = *(const bf16x8*)(fth + fo);
        bf16x8 al = *(const bf16x8*)(ftl + fo);
        float fbuf[8];
        *(float4*)(fbuf)     = *(const float4*)(x + (size_t)bc * TT + k0);
        *(float4*)(fbuf + 4) = *(const float4*)(x + (size_t)bc * TT + k0 + 4);
        bf16x8 bh, bl; cvt8(fbuf, bh, bl);
        MM3(ah, al, bh, bl, acc);
    }
    #pragma unroll
    for (int r = 0; r < 16; ++r) {
        int j = mt * 32 + (r & 3) + 8 * (r >> 2) + 4 * (l >> 5);
        xfxp[(size_t)kc * 4096 + j * 64 + bc] = acc[r];
    }
}

__global__ __launch_bounds__(256) void xfx_reduce_kernel(const float* __restrict__ xfxp,
                                                         float* __restrict__ xfxT) {
    int idx = blockIdx.x * 256 + threadIdx.x;   // 4096
    float v = 0.f;
    #pragma unroll
    for (int kc = 0; kc < KSPLIT_X; ++kc) v += xfxp[(size_t)kc * 4096 + idx];
    xfxT[idx] = v;
}

// ---------------- specmix layer-0 ----------------
__global__ __launch_bounds__(256) void specmix0_kernel(const float* __restrict__ xfxT,
                                                       const float* __restrict__ lw,
                                                       const float* __restrict__ lb,
                                                       const float* __restrict__ wr,
                                                       const float* __restrict__ wi,
                                                       ushort* __restrict__ yh,
                                                       ushort* __restrict__ yl) {
    int tid = blockIdx.x * 256 + threadIdx.x;
    int m = tid & 31, o = (tid >> 5) & 63, b = tid >> 11;
    float xvr = xfxT[m * 64 + b];
    float xvi = xfxT[(32 + m) * 64 + b];
    float c0 = (m == 0) ? (float)TT : 0.0f;
    float yr = 0.f, yim = 0.f;
    #pragma unroll 4
    for (int i = 0; i < WW; ++i) {
        float xr = lw[i] * xvr + c0 * lb[i];
        float xi = lw[i] * xvi;
        float ar = wr[((size_t)(i * 64 + o)) * 32 + m];
        float ai = wi[((size_t)(i * 64 + o)) * 32 + m];
        yr  += xr * ar - xi * ai;
        yim += xr * ai + xi * ar;
    }
    u32 pr = packf(yr), pi = packf(yim);
    size_t i0 = yfm_idx(b, o, m), i1 = yfm_idx(b, o, 32 + m);
    yh[i0] = (ushort)(pr & 0xffffu); yl[i0] = (ushort)(pr >> 16);
    yh[i1] = (ushort)(pi & 0xffffu); yl[i1] = (ushort)(pi >> 16);
}

// ---------------- specmix (standard) ----------------
__global__ __launch_bounds__(256) void specmix_kernel(const float* __restrict__ xfb,
                                                      const float* __restrict__ wr,
                                                      const float* __restrict__ wi,
                                                      ushort* __restrict__ yh,
                                                      ushort* __restrict__ yl) {
    int tid = blockIdx.x * 256 + threadIdx.x;
    int m = tid & 31, o = (tid >> 5) & 63, b = tid >> 11;
    float yr = 0.f, yim = 0.f;
    #pragma unroll 4
    for (int i = 0; i < WW; ++i) {
        float xr = xfb[((size_t)(b * 64 + m)) * 64 + i];
        float xi = xfb[((size_t)(b * 64 + 32 + m)) * 64 + i];
        float ar = wr[((size_t)(i * 64 + o)) * 32 + m];
        float ai = wi[((size_t)(i * 64 + o)) * 32 + m];
        yr  += xr * ar - xi * ai;
        yim += xr * ai + xi * ar;
    }
    u32 pr = packf(yr), pi = packf(yim);
    size_t i0 = yfm_idx(b, o, m), i1 = yfm_idx(b, o, 32 + m);
    yh[i0] = (ushort)(pr & 0xffffu); yl[i0] = (ushort)(pr >> 16);
    yh[i1] = (ushort)(pi & 0xffffu); yl[i1] = (ushort)(pi >> 16);
}

__global__ __launch_bounds__(256) void xreduce_kernel(const float* __restrict__ xfp,
                                                      float* __restrict__ xfb) {
    int idx = blockIdx.x * 256 + threadIdx.x;   // 262144
    float v = 0.f;
    #pragma unroll
    for (int kc = 0; kc < KSPLIT_L; ++kc) v += xfp[(size_t)kc * 262144 + idx];
    xfb[idx] = v;
}

// ============ fused layer: spec + pw + GELU -> hc (bf16), accumulate next-layer DFT partial ============
// hc store moved BEFORE the barrier: tile i's hc reads completed before tile i-1's barrier
// (prefetch discipline), so the store needs only the prologue/previous barrier, and its
// latency now hides under the LDS writes + barrier + DFT phase.
template<int IS_L0>
__global__ __launch_bounds__(256) void layer_kernel(ushort* __restrict__ hch,
                                                    const ushort* __restrict__ yh, const ushort* __restrict__ yl,
                                                    const ushort* __restrict__ ith, const ushort* __restrict__ itl,
                                                    const ushort* __restrict__ pwh, const ushort* __restrict__ pwl,
                                                    const float* __restrict__ pwb,
                                                    const float* __restrict__ x,
                                                    const float* __restrict__ pwlw, const float* __restrict__ pwlb,
                                                    const ushort* __restrict__ fth, const ushort* __restrict__ ftl,
                                                    float* __restrict__ xfp) {
    __shared__ ushort lhth[2][64 * 72];   // double-buffered [w][t] tile, hi plane only (pad 72)
    const int kc = blockIdx.x, b = blockIdx.y;
    const int tid = threadIdx.x, l = tid & 63, q = tid >> 6;
    const int mt = q >> 1, nt = q & 1;
    const int ltc = nt * 32 + (l & 31);
    const int kh = (l >> 5) * 8;
    f32x16 aF; ACC_ZERO(aF);

    bf16x8 pfh[4];    // prefetched hc B-frags
    if (!IS_L0) {
        const int t32g0 = (kc * 256 >> 5) + nt;
        #pragma unroll
        for (int ks = 0; ks < 4; ++ks)
            pfh[ks] = *(const bf16x8*)(hch + (((size_t)b * 128 + t32g0) * 4 + ks) * 512 + l * 8);
        __syncthreads();   // all waves' tile-0 prefetch issued before any tile-0 store
    }

    for (int tile = 0; tile < 4; ++tile) {
        const int tbase = kc * 256 + tile * 64;
        const int t32g = (tbase >> 5) + nt;
        ushort* lbh = lhth[tile & 1];
        f32x16 accA, accB; ACC_ZERO(accA); ACC_ZERO(accB);
        // spec GEMM: A=Y[b] fm, B=itab fm (L2-hot)
        #pragma unroll
        for (int ks = 0; ks < 4; ++ks) {
            size_t yo = (((size_t)b * 2 + mt) * 4 + ks) * 512 + l * 8;
            size_t io = ((size_t)t32g * 4 + ks) * 512 + l * 8;
            bf16x8 ya = *(const bf16x8*)(yh + yo);
            bf16x8 yb = *(const bf16x8*)(yl + yo);
            bf16x8 bh = *(const bf16x8*)(ith + io);
            bf16x8 bl = *(const bf16x8*)(itl + io);
            if (ks & 1) { MM3_ODD(ya, yb, bh, bl, accA, accB); }
            else        { MM3_EVEN(ya, yb, bh, bl, accA, accB); }
        }
        float xv = 0.f;
        if (!IS_L0) {
            // pw GEMM: A=pw fm (hi/lo), B=prefetched hc (bf16) -> 2-term
            #pragma unroll
            for (int ks = 0; ks < 4; ++ks) {
                size_t po = ((size_t)mt * 4 + ks) * 512 + l * 8;
                bf16x8 pa = *(const bf16x8*)(pwh + po);
                bf16x8 pb = *(const bf16x8*)(pwl + po);
                MM2(pa, pb, pfh[ks], accA, accB);
            }
            // prefetch NEXT tile's hc frags
            if (tile < 3) {
                const int t32n = t32g + 2;
                #pragma unroll
                for (int ks = 0; ks < 4; ++ks)
                    pfh[ks] = *(const bf16x8*)(hch + (((size_t)b * 128 + t32n) * 4 + ks) * 512 + l * 8);
            }
        } else {
            xv = x[(size_t)b * TT + tbase + ltc];
        }
        // epilogue (bfrn only)
        ushort ovh[16];
        #pragma unroll
        for (int rq = 0; rq < 4; ++rq) {
            int ob = mt * 32 + 8 * rq + 4 * (l >> 5);
            #pragma unroll
            for (int i = 0; i < 4; ++i) {
                float v = accA[rq * 4 + i] + accB[rq * 4 + i];
                if (IS_L0) v += pwlw[ob + i] * xv + pwlb[ob + i];
                else       v += pwb[ob + i];
                ovh[rq * 4 + i] = (ushort)bfrn(gelu_exact(v));
            }
        }
        // hc store FIRST (in-place safe: this tile's reads completed before the prior barrier;
        // latency overlaps LDS writes + barrier + DFT)
        #pragma unroll
        for (int rq = 0; rq < 4; ++rq) {
            size_t ho = (((size_t)b * 128 + t32g) * 4 + (mt * 2 + (rq >> 1))) * 512
                      + ((l & 31) + 32 * (rq & 1)) * 8 + 4 * (l >> 5);
            *(ushort4*)(hch + ho) = make_ushort4(ovh[rq*4+0], ovh[rq*4+1], ovh[rq*4+2], ovh[rq*4+3]);
        }
        // lht writes (hi only, before barrier)
        #pragma unroll
        for (int rq = 0; rq < 4; ++rq) {
            int ob = mt * 32 + 8 * rq + 4 * (l >> 5);
            #pragma unroll
            for (int i = 0; i < 4; ++i) lbh[(ob + i) * 72 + ltc] = ovh[rq * 4 + i];
        }
        __syncthreads();   // single barrier: lht visible (and orders next tile's hc-read/store pairs)
        // DFT accumulate: A=ftab fm (hi/lo), B=lht hi -> 2-term
        #pragma unroll
        for (int ks = 0; ks < 4; ++ks) {
            int k0 = ks * 16 + kh;
            size_t fo = (((size_t)((tbase >> 4) + ks)) * 2 + mt) * 512 + l * 8;
            bf16x8 ah = *(const bf16x8*)(fth + fo);
            bf16x8 al = *(const bf16x8*)(ftl + fo);
            bf16x8 bh = *(const bf16x8*)&lbh[ltc * 72 + k0];
            aF = __builtin_amdgcn_mfma_f32_32x32x16_bf16(ah, bh, aF, 0, 0, 0);
            aF = __builtin_amdgcn_mfma_f32_32x32x16_bf16(al, bh, aF, 0, 0, 0);
        }
    }
    float* dst = xfp + ((size_t)(kc * 64 + b)) * 4096;
    #pragma unroll
    for (int r = 0; r < 16; ++r) {
        int j = mt * 32 + (r & 3) + 8 * (r >> 2) + 4 * (l >> 5);
        dst[j * 64 + ltc] = aF[r];
    }
}

// ============ last layer: spec + pw + GELU + proj1(gelu) + proj2 -> sc planes ============
__global__ __launch_bounds__(256) void layer3_kernel(const ushort* __restrict__ hch,
                                                     const ushort* __restrict__ yh, const ushort* __restrict__ yl,
                                                     const ushort* __restrict__ ith, const ushort* __restrict__ itl,
                                                     const ushort* __restrict__ pwh, const ushort* __restrict__ pwl,
                                                     const float* __restrict__ pwb,
                                                     const ushort* __restrict__ p1h, const ushort* __restrict__ p1l,
                                                     const float* __restrict__ p1b,
                                                     const float* __restrict__ p2w, const float* __restrict__ p2b,
                                                     ushort* __restrict__ sch, ushort* __restrict__ scl) {
    __shared__ ushort lbh[64 * 72];
    __shared__ ushort lbl[64 * 72];
    __shared__ float red[4][64];
    const int t0 = blockIdx.x << 6, b = blockIdx.y;
    const int tid = threadIdx.x, l = tid & 63, q = tid >> 6;
    const int mt = q >> 1, nt = q & 1;
    const int ltc = nt * 32 + (l & 31);
    const int kh = (l >> 5) * 8;
    const int t32g = (t0 >> 5) + nt;
    f32x16 accA, accB; ACC_ZERO(accA); ACC_ZERO(accB);

    #pragma unroll
    for (int ks = 0; ks < 4; ++ks) {
        size_t yo = (((size_t)b * 2 + mt) * 4 + ks) * 512 + l * 8;
        size_t io = ((size_t)t32g * 4 + ks) * 512 + l * 8;
        bf16x8 ah = *(const bf16x8*)(yh + yo);
        bf16x8 al = *(const bf16x8*)(yl + yo);
        bf16x8 bh = *(const bf16x8*)(ith + io);
        bf16x8 bl = *(const bf16x8*)(itl + io);
        if (ks & 1) { MM3_ODD(ah, al, bh, bl, accA, accB); }
        else        { MM3_EVEN(ah, al, bh, bl, accA, accB); }
    }
    #pragma unroll
    for (int ks = 0; ks < 4; ++ks) {
        size_t po = ((size_t)mt * 4 + ks) * 512 + l * 8;
        size_t hi = (((size_t)b * 128 + t32g) * 4 + ks) * 512 + l * 8;
        bf16x8 ah = *(const bf16x8*)(pwh + po);
        bf16x8 al = *(const bf16x8*)(pwl + po);
        bf16x8 bh = *(const bf16x8*)(hch + hi);
        MM2(ah, al, bh, accA, accB);
    }
    // h3 tile -> lht planes only (never to HBM; hi/lo kept here, free)
    #pragma unroll
    for (int rq = 0; rq < 4; ++rq) {
        int ob = mt * 32 + 8 * rq + 4 * (l >> 5);
        #pragma unroll
        for (int i = 0; i < 4; ++i) {
            float v = accA[rq * 4 + i] + accB[rq * 4 + i] + pwb[ob + i];
            ushort h, lo_; packf2(gelu_exact(v), h, lo_);
            lbh[(ob + i) * 72 + ltc] = h;
            lbl[(ob + i) * 72 + ltc] = lo_;
        }
    }
    __syncthreads();
    // proj1 GEMM: A=p1 fm, B=lht planes — B element (k=w, col=t): [(k0+i)*72 + ltc]
    f32x16 a2; ACC_ZERO(a2);
    #pragma unroll
    for (int ks = 0; ks < 4; ++ks) {
        int k0 = ks * 16 + kh;
        size_t po = ((size_t)mt * 4 + ks) * 512 + l * 8;
        bf16x8 ah = *(const bf16x8*)(p1h + po);
        bf16x8 al = *(const bf16x8*)(p1l + po);
        union { bf16x8 v; ushort u[8]; } BH, BL;
        #pragma unroll
        for (int i = 0; i < 8; ++i) {
            BH.u[i] = lbh[(k0 + i) * 72 + ltc];
            BL.u[i] = lbl[(k0 + i) * 72 + ltc];
        }
        MM3(ah, al, BH.v, BL.v, a2);
    }
    float part = 0.f;
    #pragma unroll
    for (int r = 0; r < 16; ++r) {
        int wp = mt * 32 + (r & 3) + 8 * (r >> 2) + 4 * (l >> 5);
        part += gelu_exact(a2[r] + p1b[wp]) * p2w[wp];
    }
    red[q][l] = part;
    __syncthreads();
    if (tid < 64) {
        int hn = tid >> 5, c = tid & 31;
        float v = red[hn][c] + red[hn][c + 32] + red[2 + hn][c] + red[2 + hn][c + 32] + p2b[0];
        int t = t0 + tid;
        size_t so = ((((size_t)(t >> 4)) * 2 + (b >> 5)) * 64 + (b & 31) + 32 * ((t >> 3) & 1)) * 8 + (t & 7);
        ushort h, lo_; packf2(v, h, lo_);
        sch[so] = h; scl[so] = lo_;
    }
}

// ------------- token mixing partials (LDS-staged tokw) + reduce -------------
__global__ __launch_bounds__(256) void tok_kernel(const ushort* __restrict__ sch, const ushort* __restrict__ scl,
                                                  const float* __restrict__ tokw,
                                                  float* __restrict__ tkp) {
    __shared__ ushort twh[64][68];   // tokw tile [u_local][t_local], hi plane
    __shared__ ushort twl[64][68];   // lo plane
    const int u0 = blockIdx.x << 6, kc = blockIdx.y;
    const int tid = threadIdx.x, l = tid & 63, q = tid >> 6;
    const int mt = q >> 1, nt = q & 1;
    const int ul  = nt * 32 + (l & 31);
    const int lu  = u0 + ul;
    const int kh = (l >> 5) * 8;
    f32x16 acc; ACC_ZERO(acc);
    for (int chunk = 0; chunk < 4; ++chunk) {
        const int tchunk = kc * 256 + chunk * 64;
        __syncthreads();
        #pragma unroll
        for (int j = 0; j < 4; ++j) {
            int f = tid + j * 256;
            int u = f >> 4, c4 = (f & 15) << 2;
            float4 v = *(const float4*)(tokw + (size_t)(u0 + u) * TT + tchunk + c4);
            ushort h0, l0, h1, l1, h2, l2, h3, l3;
            packf2(v.x, h0, l0); packf2(v.y, h1, l1);
            packf2(v.z, h2, l2); packf2(v.w, h3, l3);
            *(ushort4*)&twh[u][c4] = make_ushort4(h0, h1, h2, h3);
            *(ushort4*)&twl[u][c4] = make_ushort4(l0, l1, l2, l3);
        }
        __syncthreads();
        #pragma unroll
        for (int ksl = 0; ksl < 4; ++ksl) {
            int ks = chunk * 4 + ksl;
            size_t so = (((size_t)(kc * 16 + ks) * 2 + mt) * 64 + l) * 8;
            bf16x8 ah = *(const bf16x8*)(sch + so);
            bf16x8 al = *(const bf16x8*)(scl + so);
            int kk = ksl * 16 + kh;
            bf16x8 bh = *(const bf16x8*)&twh[ul][kk];
            bf16x8 bl = *(const bf16x8*)&twl[ul][kk];
            MM3(ah, al, bh, bl, acc);
        }
    }
    #pragma unroll
    for (int r = 0; r < 16; ++r) {
        int br = mt * 32 + (r & 3) + 8 * (r >> 2) + 4 * (l >> 5);
        tkp[((size_t)(kc * 64 + br)) * OUTT + lu] = acc[r];
    }
}

__global__ __launch_bounds__(256) void tok_reduce_kernel(const float* __restrict__ tkp,
                                                         const float* __restrict__ tokb,
                                                         float* __restrict__ out) {
    int idx = blockIdx.x * 256 + threadIdx.x;
    int u = idx & (OUTT - 1);
    float v = tokb[u];
    #pragma unroll
    for (int kc = 0; kc < KSPLIT_TOK; ++kc) v += tkp[(size_t)kc * 262144 + idx];
    out[idx] = v;
}

extern "C" void kernel_launch(void* const* d_in, const int* in_sizes, int n_in,
                              void* d_out, int out_size, void* d_ws, size_t ws_size,
                              hipStream_t stream) {
    const float* x    = (const float*)d_in[0];
    const float* lw   = (const float*)d_in[1];
    const float* lb   = (const float*)d_in[2];
    const float* swr  = (const float*)d_in[3];
    const float* swi  = (const float*)d_in[4];
    const float* pww  = (const float*)d_in[5];
    const float* pwb  = (const float*)d_in[6];
    const float* p1w  = (const float*)d_in[7];
    const float* p1b  = (const float*)d_in[8];
    const float* p2w  = (const float*)d_in[9];
    const float* p2b  = (const float*)d_in[10];
    const float* tokw = (const float*)d_in[11];
    const float* tokb = (const float*)d_in[12];
    float* out = (float*)d_out;

    float* ws = (float*)d_ws;
    ushort* hch  = (ushort*)(ws + OFF_HCH);
    ushort* fth  = (ushort*)(ws + OFF_FTH);
    ushort* ftl  = (ushort*)(ws + OFF_FTL);
    ushort* ith  = (ushort*)(ws + OFF_ITH);
    ushort* itl  = (ushort*)(ws + OFF_ITL);
    ushort* pwh  = (ushort*)(ws + OFF_PWH);
    ushort* pwl  = (ushort*)(ws + OFF_PWL);
    ushort* p1h  = (ushort*)(ws + OFF_P1H);
    ushort* p1l  = (ushort*)(ws + OFF_P1L);
    ushort* yh   = (ushort*)(ws + OFF_YH);
    ushort* yl   = (ushort*)(ws + OFF_YL);
    float*  xfp  = ws + OFF_XFP;
    float*  xfb  = ws + OFF_XFB;
    ushort* sch  = (ushort*)(ws + OFF_SCH);
    ushort* scl  = (ushort*)(ws + OFF_SCL);
    float*  pwlw = ws + OFF_PWLW;
    float*  pwlb = ws + OFF_PWLB;
    float*  lut  = ws + OFF_XFXP;       // 8192 floats
    float*  xfxp = ws + OFF_XFP;        // [32][4096] f32, free until layer0
    float*  xfxT = ws + OFF_XFXT;

    sincos_lut_kernel<<<16, 256, 0, stream>>>(lut);
    build_tables_kernel<<<1024, 256, 0, stream>>>(lut, fth, ftl, ith, itl);
    wconv_kernel<<<81, 256, 0, stream>>>(pww, p1w, lw, lb, pwb, pwh, pwl, p1h, p1l, pwlw, pwlb);

    // layer 0 input spectrum from rank-1 lift
    dftx_kernel<<<KSPLIT_X, 256, 0, stream>>>(x, fth, ftl, xfxp);
    xfx_reduce_kernel<<<16, 256, 0, stream>>>(xfxp, xfxT);
    specmix0_kernel<<<512, 256, 0, stream>>>(xfxT, lw, lb, swr, swi, yh, yl);

    // layer 0 (no hc read) — also produces layer-1 DFT partials
    layer_kernel<1><<<dim3(KSPLIT_L, BB), 256, 0, stream>>>(
        hch, yh, yl, ith, itl, pwh, pwl, pwb, x, pwlw, pwlb, fth, ftl, xfp);

    for (int l = 1; l < NLAYER; ++l) {
        xreduce_kernel<<<1024, 256, 0, stream>>>(xfp, xfb);
        specmix_kernel<<<512, 256, 0, stream>>>(
            xfb, swr + (size_t)l * WW * WW * MODES, swi + (size_t)l * WW * WW * MODES, yh, yl);
        if (l < NLAYER - 1) {
            layer_kernel<0><<<dim3(KSPLIT_L, BB), 256, 0, stream>>>(
                hch, yh, yl, ith, itl, pwh + (size_t)l * 4096, pwl + (size_t)l * 4096,
                pwb + (size_t)l * 64, x, pwlw, pwlb, fth, ftl, xfp);
        } else {
            layer3_kernel<<<dim3(TT / 64, BB), 256, 0, stream>>>(
                hch, yh, yl, ith, itl, pwh + (size_t)l * 4096, pwl + (size_t)l * 4096,
                pwb + (size_t)l * 64, p1h, p1l, p1b, p2w, p2b, sch, scl);
        }
    }

    tok_kernel<<<dim3(OUTT / 64, KSPLIT_TOK), 256, 0, stream>>>(sch, scl, tokw, xfp);
    tok_reduce_kernel<<<1024, 256, 0, stream>>>(xfp, tokb, out);
}

// Round 20
// 223.328 us; speedup vs baseline: 1.0862x; 1.0862x over previous
//
#include <hip/hip_runtime.h>
#include <math.h>
#include <stdint.h>

#define BB 64
#define TT 4096
#define WW 64
#define MODES 32
#define NLAYER 4
#define KSPLIT_X 32    // dftx split (grid 32)
#define KSPLIT_TOK 16  // tok split (grid 1024)
#define KSPLIT_L 16    // layer-kernel t-chunk split (1024 blocks)
#define OUTT 4096

typedef uint32_t u32;
typedef __attribute__((ext_vector_type(8))) short bf16x8;
typedef __attribute__((ext_vector_type(16))) float f32x16;

// ws layout (float offsets).  Tables as bf16 hi/lo planes, fragment-major (fm):
//   A-frag:  lane l holds row (l&31)+32*half, k = kbase + (l>>5)*8 + pos
//   B-frag:  lane l holds col (l&31)+32*half, k = kbase + (l>>5)*8 + pos
// hc: SINGLE bf16 plane — h is uniformly bf16 after each layer (pw + DFT branches).
// hc fm (ushort idx): element (b,t,w) at ((b*128+(t>>5))*4+(w>>4))*512 + ((t&31)+32*((w>>3)&1))*8 + (w&7)
#define OFF_HCH  0            // hch fm, 16,777,216 ushort (8,388,608 f)
#define OFF_FTH  16777216     // ftab fm [256 ttile][2 jhalf][64][8] ushort
#define OFF_FTL  16908288
#define OFF_ITH  17039360     // itab fm [128 t32][4 kt][64][8] ushort
#define OFF_ITL  17170432
#define OFF_PWH  17301504     // pw fm [4 layer][2 ohalf][4 kt][64][8] ushort
#define OFF_PWL  17309696
#define OFF_P1H  17317888     // p1 fm [2][4][64][8] ushort
#define OFF_P1L  17319936
#define OFF_YH   17321984     // Y fm [64 b][2 ohalf][4 kt][64][8] ushort
#define OFF_YL   17453056
#define OFF_XFP  17584128     // xfPart [16][64][64][64] f32 (4,194,304); dftx partials (pre-L0) + tok partials reuse
#define OFF_XFB  21778432     // xfb [64][64][64] f32
#define OFF_SCH  22040576     // sc hi fm [256 ttile][2 bhalf][64][8] ushort (131072 f)
#define OFF_SCL  22171648     // sc lo fm
#define OFF_PWLW 22302720     // [64]
#define OFF_PWLB 22302784     // [64]
#define OFF_XFXP 22302848     // sincos LUT (8192 f)
#define OFF_XFXT 22335616     // [64][64] f32

// fast exact-form GELU: branch-free A&S 7.1.26 erf, |err(erf)| <= 1.5e-7
__device__ __forceinline__ float gelu_exact(float x) {
    float ax = fabsf(x);
    float z  = ax * 0.70710678118654752f;
    float t  = __builtin_amdgcn_rcpf(fmaf(0.3275911f, z, 1.0f));
    float ex = __builtin_amdgcn_exp2f(z * z * -1.44269504088896341f);
    float p  = fmaf(fmaf(fmaf(fmaf(1.061405429f, t, -1.453152027f),
                              t, 1.421413741f), t, -0.284496736f), t, 0.254829592f);
    float er = 1.0f - p * t * ex;
    er = copysignf(er, x);
    return 0.5f * x * (1.0f + er);
}
__device__ __forceinline__ u32 bfrn(float f) {
    u32 u = __float_as_uint(f);
    return (u + 0x7fffu + ((u >> 16) & 1u)) >> 16;
}
__device__ __forceinline__ void packf2(float f, ushort& hi, ushort& lo) {
    u32 h = bfrn(f);
    float r = f - __uint_as_float(h << 16);
    hi = (ushort)h;
    lo = (ushort)bfrn(r);
}
__device__ __forceinline__ u32 packf(float f) {
    ushort h, l; packf2(f, h, l);
    return (u32)h | ((u32)l << 16);
}
__device__ __forceinline__ void cvt8(const float* f, bf16x8& hi, bf16x8& lo) {
    union { bf16x8 v; ushort u[8]; } H, L;
    #pragma unroll
    for (int i = 0; i < 8; ++i) {
        ushort h, l; packf2(f[i], h, l);
        H.u[i] = h; L.u[i] = l;
    }
    hi = H.v; lo = L.v;
}

#define MM3(ah, al, bh, bl, acc)                                          \
    acc = __builtin_amdgcn_mfma_f32_32x32x16_bf16(ah, bh, acc, 0, 0, 0);  \
    acc = __builtin_amdgcn_mfma_f32_32x32x16_bf16(ah, bl, acc, 0, 0, 0);  \
    acc = __builtin_amdgcn_mfma_f32_32x32x16_bf16(al, bh, acc, 0, 0, 0);

// two-chain variants
#define MM3_EVEN(ah, al, bh, bl, accA, accB)                                \
    accA = __builtin_amdgcn_mfma_f32_32x32x16_bf16(ah, bh, accA, 0, 0, 0);  \
    accB = __builtin_amdgcn_mfma_f32_32x32x16_bf16(ah, bl, accB, 0, 0, 0);  \
    accA = __builtin_amdgcn_mfma_f32_32x32x16_bf16(al, bh, accA, 0, 0, 0);
#define MM3_ODD(ah, al, bh, bl, accA, accB)                                 \
    accB = __builtin_amdgcn_mfma_f32_32x32x16_bf16(ah, bh, accB, 0, 0, 0);  \
    accA = __builtin_amdgcn_mfma_f32_32x32x16_bf16(ah, bl, accA, 0, 0, 0);  \
    accB = __builtin_amdgcn_mfma_f32_32x32x16_bf16(al, bh, accB, 0, 0, 0);
// 2-term (B hi-only), balanced across chains
#define MM2(ah, al, bh, accA, accB)                                         \
    accA = __builtin_amdgcn_mfma_f32_32x32x16_bf16(ah, bh, accA, 0, 0, 0);  \
    accB = __builtin_amdgcn_mfma_f32_32x32x16_bf16(al, bh, accB, 0, 0, 0);

#define ACC_ZERO(acc) { _Pragma("unroll") for (int _i = 0; _i < 16; ++_i) acc[_i] = 0.0f; }

// ---------------- sincos LUT ----------------
__global__ __launch_bounds__(256) void sincos_lut_kernel(float* __restrict__ lut) {
    int a = blockIdx.x * 256 + threadIdx.x;    // 0..4095
    const float w0 = 6.28318530717958647692f / (float)TT;
    float s, c; sincosf((float)a * w0, &s, &c);
    lut[a * 2]     = c;
    lut[a * 2 + 1] = s;
}

// ---------------- tables (fragment-major, from LUT) ----------------
__global__ __launch_bounds__(256) void build_tables_kernel(const float* __restrict__ lut,
                                                           ushort* __restrict__ fth, ushort* __restrict__ ftl,
                                                           ushort* __restrict__ ith, ushort* __restrict__ itl) {
    const int idx = blockIdx.x * 256 + threadIdx.x;   // 0..262143
    {   // ftab fm: A-frag rows j, k=t.
        int pos = idx & 7, l = (idx >> 3) & 63, half = (idx >> 9) & 1, ttile = idx >> 10;
        int j = half * 32 + (l & 31);
        int t = ttile * 16 + (l >> 5) * 8 + pos;
        int m = j & 31;
        int a = (m * t) & (TT - 1);
        float c = lut[a * 2], s = lut[a * 2 + 1];
        u32 p = packf((j < 32) ? c : -s);
        fth[idx] = (ushort)(p & 0xffffu); ftl[idx] = (ushort)(p >> 16);
    }
    {   // itab fm: B-frag cols t, k=j.
        int pos = idx & 7, l = (idx >> 3) & 63, kt = (idx >> 9) & 3, t32 = idx >> 11;
        int t = t32 * 32 + (l & 31);
        int j = kt * 16 + (l >> 5) * 8 + pos;
        int m = j & 31;
        int a = (m * t) & (TT - 1);
        float c = lut[a * 2], s = lut[a * 2 + 1];
        float v;
        if (j == 0)       v = 1.0f / (float)TT;
        else if (j < 32)  v = (2.0f / (float)TT) * c;
        else if (j == 32) v = 0.0f;
        else              v = -(2.0f / (float)TT) * s;
        u32 p = packf(v);
        ith[idx] = (ushort)(p & 0xffffu); itl[idx] = (ushort)(p >> 16);
    }
}

// ---------------- weights: fm planes + layer-0 rank-1 folds ----------------
__global__ __launch_bounds__(256) void wconv_kernel(const float* __restrict__ pww, const float* __restrict__ p1w,
                                                    const float* __restrict__ lw, const float* __restrict__ lb,
                                                    const float* __restrict__ pwb,
                                                    ushort* __restrict__ pwh, ushort* __restrict__ pwl,
                                                    ushort* __restrict__ p1h, ushort* __restrict__ p1l,
                                                    float* __restrict__ pwlw, float* __restrict__ pwlb) {
    int idx = blockIdx.x * 256 + threadIdx.x;
    if (idx < NLAYER * 4096) {
        int pos = idx & 7, l = (idx >> 3) & 63, kt = (idx >> 9) & 3, half = (idx >> 11) & 1, layer = idx >> 12;
        int o = half * 32 + (l & 31);
        int w = kt * 16 + (l >> 5) * 8 + pos;
        u32 p = packf(pww[layer * 4096 + o * 64 + w]);
        pwh[idx] = (ushort)(p & 0xffffu); pwl[idx] = (ushort)(p >> 16);
    } else if (idx < NLAYER * 4096 + 4096) {
        int k = idx - NLAYER * 4096;
        int pos = k & 7, l = (k >> 3) & 63, kt = (k >> 9) & 3, half = (k >> 11) & 1;
        int wp = half * 32 + (l & 31);
        int w = kt * 16 + (l >> 5) * 8 + pos;
        u32 p = packf(p1w[wp * 64 + w]);
        p1h[k] = (ushort)(p & 0xffffu); p1l[k] = (ushort)(p >> 16);
    } else if (idx < NLAYER * 4096 + 4096 + 64) {
        int o = idx - (NLAYER * 4096 + 4096);
        float aw = 0.f, ab = 0.f;
        for (int w = 0; w < 64; ++w) {
            float pv = pww[o * 64 + w];   // layer 0
            aw += pv * lw[w];
            ab += pv * lb[w];
        }
        pwlw[o] = aw;
        pwlb[o] = ab + pwb[o];
    }
}

// Y fm write helper
__device__ __forceinline__ size_t yfm_idx(int b, int o, int j) {
    return ((((size_t)b * 2 + (o >> 5)) * 4 + (j >> 4)) * 64 + (o & 31) + 32 * ((j >> 3) & 1)) * 8 + (j & 7);
}

// ---------------- dftx: xfxp[kc][j][b] over 128-t chunks (grid 32) ----------------
__global__ __launch_bounds__(256) void dftx_kernel(const float* __restrict__ x,
                                                   const ushort* __restrict__ fth,
                                                   const ushort* __restrict__ ftl,
                                                   float* __restrict__ xfxp) {
    const int kc = blockIdx.x;
    const int tid = threadIdx.x, l = tid & 63, q = tid >> 6;
    const int mt = q >> 1, nt = q & 1;
    const int bc = nt * 32 + (l & 31);
    const int kh = (l >> 5) * 8;
    f32x16 acc; ACC_ZERO(acc);
    for (int ks = 0; ks < 4096 / KSPLIT_X / 16; ++ks) {
        int k0 = kc * (4096 / KSPLIT_X) + ks * 16 + kh;
        size_t fo = (((size_t)(kc * (4096 / KSPLIT_X / 16) + ks) * 2 + mt) * 64 + l) * 8;
        bf16x8 ah = *(const bf16x8*)(fth + fo);
        bf16x8 al = *(const bf16x8*)(ftl + fo);
        float fbuf[8];
        *(float4*)(fbuf)     = *(const float4*)(x + (size_t)bc * TT + k0);
        *(float4*)(fbuf + 4) = *(const float4*)(x + (size_t)bc * TT + k0 + 4);
        bf16x8 bh, bl; cvt8(fbuf, bh, bl);
        MM3(ah, al, bh, bl, acc);
    }
    #pragma unroll
    for (int r = 0; r < 16; ++r) {
        int j = mt * 32 + (r & 3) + 8 * (r >> 2) + 4 * (l >> 5);
        xfxp[(size_t)kc * 4096 + j * 64 + bc] = acc[r];
    }
}

__global__ __launch_bounds__(256) void xfx_reduce_kernel(const float* __restrict__ xfxp,
                                                         float* __restrict__ xfxT) {
    int idx = blockIdx.x * 256 + threadIdx.x;   // 4096
    float v = 0.f;
    #pragma unroll
    for (int kc = 0; kc < KSPLIT_X; ++kc) v += xfxp[(size_t)kc * 4096 + idx];
    xfxT[idx] = v;
}

// ---------------- specmix layer-0 ----------------
__global__ __launch_bounds__(256) void specmix0_kernel(const float* __restrict__ xfxT,
                                                       const float* __restrict__ lw,
                                                       const float* __restrict__ lb,
                                                       const float* __restrict__ wr,
                                                       const float* __restrict__ wi,
                                                       ushort* __restrict__ yh,
                                                       ushort* __restrict__ yl) {
    int tid = blockIdx.x * 256 + threadIdx.x;
    int m = tid & 31, o = (tid >> 5) & 63, b = tid >> 11;
    float xvr = xfxT[m * 64 + b];
    float xvi = xfxT[(32 + m) * 64 + b];
    float c0 = (m == 0) ? (float)TT : 0.0f;
    float yr = 0.f, yim = 0.f;
    #pragma unroll 4
    for (int i = 0; i < WW; ++i) {
        float xr = lw[i] * xvr + c0 * lb[i];
        float xi = lw[i] * xvi;
        float ar = wr[((size_t)(i * 64 + o)) * 32 + m];
        float ai = wi[((size_t)(i * 64 + o)) * 32 + m];
        yr  += xr * ar - xi * ai;
        yim += xr * ai + xi * ar;
    }
    u32 pr = packf(yr), pi = packf(yim);
    size_t i0 = yfm_idx(b, o, m), i1 = yfm_idx(b, o, 32 + m);
    yh[i0] = (ushort)(pr & 0xffffu); yl[i0] = (ushort)(pr >> 16);
    yh[i1] = (ushort)(pi & 0xffffu); yl[i1] = (ushort)(pi >> 16);
}

// ---------------- specmix (standard) ----------------
__global__ __launch_bounds__(256) void specmix_kernel(const float* __restrict__ xfb,
                                                      const float* __restrict__ wr,
                                                      const float* __restrict__ wi,
                                                      ushort* __restrict__ yh,
                                                      ushort* __restrict__ yl) {
    int tid = blockIdx.x * 256 + threadIdx.x;
    int m = tid & 31, o = (tid >> 5) & 63, b = tid >> 11;
    float yr = 0.f, yim = 0.f;
    #pragma unroll 4
    for (int i = 0; i < WW; ++i) {
        float xr = xfb[((size_t)(b * 64 + m)) * 64 + i];
        float xi = xfb[((size_t)(b * 64 + 32 + m)) * 64 + i];
        float ar = wr[((size_t)(i * 64 + o)) * 32 + m];
        float ai = wi[((size_t)(i * 64 + o)) * 32 + m];
        yr  += xr * ar - xi * ai;
        yim += xr * ai + xi * ar;
    }
    u32 pr = packf(yr), pi = packf(yim);
    size_t i0 = yfm_idx(b, o, m), i1 = yfm_idx(b, o, 32 + m);
    yh[i0] = (ushort)(pr & 0xffffu); yl[i0] = (ushort)(pr >> 16);
    yh[i1] = (ushort)(pi & 0xffffu); yl[i1] = (ushort)(pi >> 16);
}

__global__ __launch_bounds__(256) void xreduce_kernel(const float* __restrict__ xfp,
                                                      float* __restrict__ xfb) {
    int idx = blockIdx.x * 256 + threadIdx.x;   // 262144
    float v = 0.f;
    #pragma unroll
    for (int kc = 0; kc < KSPLIT_L; ++kc) v += xfp[(size_t)kc * 262144 + idx];
    xfb[idx] = v;
}

// ============ fused layer: spec + pw + GELU -> hc (bf16), accumulate next-layer DFT partial ============
template<int IS_L0>
__global__ __launch_bounds__(256) void layer_kernel(ushort* __restrict__ hch,
                                                    const ushort* __restrict__ yh, const ushort* __restrict__ yl,
                                                    const ushort* __restrict__ ith, const ushort* __restrict__ itl,
                                                    const ushort* __restrict__ pwh, const ushort* __restrict__ pwl,
                                                    const float* __restrict__ pwb,
                                                    const float* __restrict__ x,
                                                    const float* __restrict__ pwlw, const float* __restrict__ pwlb,
                                                    const ushort* __restrict__ fth, const ushort* __restrict__ ftl,
                                                    float* __restrict__ xfp) {
    __shared__ ushort lhth[2][64 * 72];   // double-buffered [w][t] tile, hi plane only (pad 72)
    const int kc = blockIdx.x, b = blockIdx.y;
    const int tid = threadIdx.x, l = tid & 63, q = tid >> 6;
    const int mt = q >> 1, nt = q & 1;
    const int ltc = nt * 32 + (l & 31);
    const int kh = (l >> 5) * 8;
    f32x16 aF; ACC_ZERO(aF);

    bf16x8 pfh[4];    // prefetched hc B-frags
    if (!IS_L0) {
        const int t32g0 = (kc * 256 >> 5) + nt;
        #pragma unroll
        for (int ks = 0; ks < 4; ++ks)
            pfh[ks] = *(const bf16x8*)(hch + (((size_t)b * 128 + t32g0) * 4 + ks) * 512 + l * 8);
    }

    for (int tile = 0; tile < 4; ++tile) {
        const int tbase = kc * 256 + tile * 64;
        const int t32g = (tbase >> 5) + nt;
        ushort* lbh = lhth[tile & 1];
        f32x16 accA, accB; ACC_ZERO(accA); ACC_ZERO(accB);
        // spec GEMM: A=Y[b] fm, B=itab fm (L2-hot)
        #pragma unroll
        for (int ks = 0; ks < 4; ++ks) {
            size_t yo = (((size_t)b * 2 + mt) * 4 + ks) * 512 + l * 8;
            size_t io = ((size_t)t32g * 4 + ks) * 512 + l * 8;
            bf16x8 ya = *(const bf16x8*)(yh + yo);
            bf16x8 yb = *(const bf16x8*)(yl + yo);
            bf16x8 bh = *(const bf16x8*)(ith + io);
            bf16x8 bl = *(const bf16x8*)(itl + io);
            if (ks & 1) { MM3_ODD(ya, yb, bh, bl, accA, accB); }
            else        { MM3_EVEN(ya, yb, bh, bl, accA, accB); }
        }
        float xv = 0.f;
        if (!IS_L0) {
            // pw GEMM: A=pw fm (hi/lo), B=prefetched hc (bf16) -> 2-term
            #pragma unroll
            for (int ks = 0; ks < 4; ++ks) {
                size_t po = ((size_t)mt * 4 + ks) * 512 + l * 8;
                bf16x8 pa = *(const bf16x8*)(pwh + po);
                bf16x8 pb = *(const bf16x8*)(pwl + po);
                MM2(pa, pb, pfh[ks], accA, accB);
            }
            // prefetch NEXT tile's hc frags
            if (tile < 3) {
                const int t32n = t32g + 2;
                #pragma unroll
                for (int ks = 0; ks < 4; ++ks)
                    pfh[ks] = *(const bf16x8*)(hch + (((size_t)b * 128 + t32n) * 4 + ks) * 512 + l * 8);
            }
        } else {
            xv = x[(size_t)b * TT + tbase + ltc];
        }
        // epilogue (bfrn only; overlaps prefetch in flight)
        ushort ovh[16];
        #pragma unroll
        for (int rq = 0; rq < 4; ++rq) {
            int ob = mt * 32 + 8 * rq + 4 * (l >> 5);
            #pragma unroll
            for (int i = 0; i < 4; ++i) {
                float v = accA[rq * 4 + i] + accB[rq * 4 + i];
                if (IS_L0) v += pwlw[ob + i] * xv + pwlb[ob + i];
                else       v += pwb[ob + i];
                ovh[rq * 4 + i] = (ushort)bfrn(gelu_exact(v));
            }
        }
        // lht writes (hi only, before barrier)
        #pragma unroll
        for (int rq = 0; rq < 4; ++rq) {
            int ob = mt * 32 + 8 * rq + 4 * (l >> 5);
            #pragma unroll
            for (int i = 0; i < 4; ++i) lbh[(ob + i) * 72 + ltc] = ovh[rq * 4 + i];
        }
        __syncthreads();   // single barrier: drains vmcnt (hc reads done) + lgkmcnt (lht visible)
        // hc store (after bar -> in-place safe)
        #pragma unroll
        for (int rq = 0; rq < 4; ++rq) {
            size_t ho = (((size_t)b * 128 + t32g) * 4 + (mt * 2 + (rq >> 1))) * 512
                      + ((l & 31) + 32 * (rq & 1)) * 8 + 4 * (l >> 5);
            *(ushort4*)(hch + ho) = make_ushort4(ovh[rq*4+0], ovh[rq*4+1], ovh[rq*4+2], ovh[rq*4+3]);
        }
        // DFT accumulate: A=ftab fm (hi/lo), B=lht hi -> 2-term
        #pragma unroll
        for (int ks = 0; ks < 4; ++ks) {
            int k0 = ks * 16 + kh;
            size_t fo = (((size_t)((tbase >> 4) + ks)) * 2 + mt) * 512 + l * 8;
            bf16x8 ah = *(const bf16x8*)(fth + fo);
            bf16x8 al = *(const bf16x8*)(ftl + fo);
            bf16x8 bh = *(const bf16x8*)&lbh[ltc * 72 + k0];
            aF = __builtin_amdgcn_mfma_f32_32x32x16_bf16(ah, bh, aF, 0, 0, 0);
            aF = __builtin_amdgcn_mfma_f32_32x32x16_bf16(al, bh, aF, 0, 0, 0);
        }
    }
    float* dst = xfp + ((size_t)(kc * 64 + b)) * 4096;
    #pragma unroll
    for (int r = 0; r < 16; ++r) {
        int j = mt * 32 + (r & 3) + 8 * (r >> 2) + 4 * (l >> 5);
        dst[j * 64 + ltc] = aF[r];
    }
}

// ============ last layer: spec + pw + GELU + proj1(gelu) + proj2 -> sc planes ============
__global__ __launch_bounds__(256) void layer3_kernel(const ushort* __restrict__ hch,
                                                     const ushort* __restrict__ yh, const ushort* __restrict__ yl,
                                                     const ushort* __restrict__ ith, const ushort* __restrict__ itl,
                                                     const ushort* __restrict__ pwh, const ushort* __restrict__ pwl,
                                                     const float* __restrict__ pwb,
                                                     const ushort* __restrict__ p1h, const ushort* __restrict__ p1l,
                                                     const float* __restrict__ p1b,
                                                     const float* __restrict__ p2w, const float* __restrict__ p2b,
                                                     ushort* __restrict__ sch, ushort* __restrict__ scl) {
    __shared__ ushort lbh[64 * 72];
    __shared__ ushort lbl[64 * 72];
    __shared__ float red[4][64];
    const int t0 = blockIdx.x << 6, b = blockIdx.y;
    const int tid = threadIdx.x, l = tid & 63, q = tid >> 6;
    const int mt = q >> 1, nt = q & 1;
    const int ltc = nt * 32 + (l & 31);
    const int kh = (l >> 5) * 8;
    const int t32g = (t0 >> 5) + nt;
    f32x16 accA, accB; ACC_ZERO(accA); ACC_ZERO(accB);

    #pragma unroll
    for (int ks = 0; ks < 4; ++ks) {
        size_t yo = (((size_t)b * 2 + mt) * 4 + ks) * 512 + l * 8;
        size_t io = ((size_t)t32g * 4 + ks) * 512 + l * 8;
        bf16x8 ah = *(const bf16x8*)(yh + yo);
        bf16x8 al = *(const bf16x8*)(yl + yo);
        bf16x8 bh = *(const bf16x8*)(ith + io);
        bf16x8 bl = *(const bf16x8*)(itl + io);
        if (ks & 1) { MM3_ODD(ah, al, bh, bl, accA, accB); }
        else        { MM3_EVEN(ah, al, bh, bl, accA, accB); }
    }
    #pragma unroll
    for (int ks = 0; ks < 4; ++ks) {
        size_t po = ((size_t)mt * 4 + ks) * 512 + l * 8;
        size_t hi = (((size_t)b * 128 + t32g) * 4 + ks) * 512 + l * 8;
        bf16x8 ah = *(const bf16x8*)(pwh + po);
        bf16x8 al = *(const bf16x8*)(pwl + po);
        bf16x8 bh = *(const bf16x8*)(hch + hi);
        MM2(ah, al, bh, accA, accB);
    }
    // h3 tile -> lht planes only (never to HBM; keep hi/lo here, it's free)
    #pragma unroll
    for (int rq = 0; rq < 4; ++rq) {
        int ob = mt * 32 + 8 * rq + 4 * (l >> 5);
        #pragma unroll
        for (int i = 0; i < 4; ++i) {
            float v = accA[rq * 4 + i] + accB[rq * 4 + i] + pwb[ob + i];
            ushort h, lo_; packf2(gelu_exact(v), h, lo_);
            lbh[(ob + i) * 72 + ltc] = h;
            lbl[(ob + i) * 72 + ltc] = lo_;
        }
    }
    __syncthreads();
    // proj1 GEMM: A=p1 fm, B=lht planes — B element (k=w, col=t): [(k0+i)*72 + ltc]
    f32x16 a2; ACC_ZERO(a2);
    #pragma unroll
    for (int ks = 0; ks < 4; ++ks) {
        int k0 = ks * 16 + kh;
        size_t po = ((size_t)mt * 4 + ks) * 512 + l * 8;
        bf16x8 ah = *(const bf16x8*)(p1h + po);
        bf16x8 al = *(const bf16x8*)(p1l + po);
        union { bf16x8 v; ushort u[8]; } BH, BL;
        #pragma unroll
        for (int i = 0; i < 8; ++i) {
            BH.u[i] = lbh[(k0 + i) * 72 + ltc];
            BL.u[i] = lbl[(k0 + i) * 72 + ltc];
        }
        MM3(ah, al, BH.v, BL.v, a2);
    }
    float part = 0.f;
    #pragma unroll
    for (int r = 0; r < 16; ++r) {
        int wp = mt * 32 + (r & 3) + 8 * (r >> 2) + 4 * (l >> 5);
        part += gelu_exact(a2[r] + p1b[wp]) * p2w[wp];
    }
    red[q][l] = part;
    __syncthreads();
    if (tid < 64) {
        int hn = tid >> 5, c = tid & 31;
        float v = red[hn][c] + red[hn][c + 32] + red[2 + hn][c] + red[2 + hn][c + 32] + p2b[0];
        int t = t0 + tid;
        size_t so = ((((size_t)(t >> 4)) * 2 + (b >> 5)) * 64 + (b & 31) + 32 * ((t >> 3) & 1)) * 8 + (t & 7);
        ushort h, lo_; packf2(v, h, lo_);
        sch[so] = h; scl[so] = lo_;
    }
}

// ------------- token mixing partials (LDS-staged tokw) + reduce -------------
__global__ __launch_bounds__(256) void tok_kernel(const ushort* __restrict__ sch, const ushort* __restrict__ scl,
                                                  const float* __restrict__ tokw,
                                                  float* __restrict__ tkp) {
    __shared__ ushort twh[64][68];   // tokw tile [u_local][t_local], hi plane (pad 4 -> 2-way bank, free)
    __shared__ ushort twl[64][68];   // lo plane
    const int u0 = blockIdx.x << 6, kc = blockIdx.y;
    const int tid = threadIdx.x, l = tid & 63, q = tid >> 6;
    const int mt = q >> 1, nt = q & 1;
    const int ul  = nt * 32 + (l & 31);          // local u (B col)
    const int lu  = u0 + ul;                     // global u
    const int kh = (l >> 5) * 8;
    f32x16 acc; ACC_ZERO(acc);
    for (int chunk = 0; chunk < 4; ++chunk) {    // 4 x 64-t chunks cover this block's 256-t slab
        const int tchunk = kc * 256 + chunk * 64;
        __syncthreads();                          // prev chunk's reads done before overwrite
        // stage 64u x 64t f32 -> bf16 hi/lo planes (coalesced: 16 threads x 16B per row)
        #pragma unroll
        for (int j = 0; j < 4; ++j) {
            int f = tid + j * 256;                // float4 id 0..1023
            int u = f >> 4, c4 = (f & 15) << 2;
            float4 v = *(const float4*)(tokw + (size_t)(u0 + u) * TT + tchunk + c4);
            ushort h0, l0, h1, l1, h2, l2, h3, l3;
            packf2(v.x, h0, l0); packf2(v.y, h1, l1);
            packf2(v.z, h2, l2); packf2(v.w, h3, l3);
            *(ushort4*)&twh[u][c4] = make_ushort4(h0, h1, h2, h3);
            *(ushort4*)&twl[u][c4] = make_ushort4(l0, l1, l2, l3);
        }
        __syncthreads();
        // 4 MFMA k-steps per chunk; A=sc fm (global, coalesced), B=tokw from LDS
        #pragma unroll
        for (int ksl = 0; ksl < 4; ++ksl) {
            int ks = chunk * 4 + ksl;             // global t16-tile within this kc slab
            size_t so = (((size_t)(kc * 16 + ks) * 2 + mt) * 64 + l) * 8;
            bf16x8 ah = *(const bf16x8*)(sch + so);
            bf16x8 al = *(const bf16x8*)(scl + so);
            int kk = ksl * 16 + kh;
            bf16x8 bh = *(const bf16x8*)&twh[ul][kk];
            bf16x8 bl = *(const bf16x8*)&twl[ul][kk];
            MM3(ah, al, bh, bl, acc);
        }
    }
    #pragma unroll
    for (int r = 0; r < 16; ++r) {
        int br = mt * 32 + (r & 3) + 8 * (r >> 2) + 4 * (l >> 5);
        tkp[((size_t)(kc * 64 + br)) * OUTT + lu] = acc[r];
    }
}

__global__ __launch_bounds__(256) void tok_reduce_kernel(const float* __restrict__ tkp,
                                                         const float* __restrict__ tokb,
                                                         float* __restrict__ out) {
    int idx = blockIdx.x * 256 + threadIdx.x;
    int u = idx & (OUTT - 1);
    float v = tokb[u];
    #pragma unroll
    for (int kc = 0; kc < KSPLIT_TOK; ++kc) v += tkp[(size_t)kc * 262144 + idx];
    out[idx] = v;
}

extern "C" void kernel_launch(void* const* d_in, const int* in_sizes, int n_in,
                              void* d_out, int out_size, void* d_ws, size_t ws_size,
                              hipStream_t stream) {
    const float* x    = (const float*)d_in[0];
    const float* lw   = (const float*)d_in[1];
    const float* lb   = (const float*)d_in[2];
    const float* swr  = (const float*)d_in[3];
    const float* swi  = (const float*)d_in[4];
    const float* pww  = (const float*)d_in[5];
    const float* pwb  = (const float*)d_in[6];
    const float* p1w  = (const float*)d_in[7];
    const float* p1b  = (const float*)d_in[8];
    const float* p2w  = (const float*)d_in[9];
    const float* p2b  = (const float*)d_in[10];
    const float* tokw = (const float*)d_in[11];
    const float* tokb = (const float*)d_in[12];
    float* out = (float*)d_out;

    float* ws = (float*)d_ws;
    ushort* hch  = (ushort*)(ws + OFF_HCH);
    ushort* fth  = (ushort*)(ws + OFF_FTH);
    ushort* ftl  = (ushort*)(ws + OFF_FTL);
    ushort* ith  = (ushort*)(ws + OFF_ITH);
    ushort* itl  = (ushort*)(ws + OFF_ITL);
    ushort* pwh  = (ushort*)(ws + OFF_PWH);
    ushort* pwl  = (ushort*)(ws + OFF_PWL);
    ushort* p1h  = (ushort*)(ws + OFF_P1H);
    ushort* p1l  = (ushort*)(ws + OFF_P1L);
    ushort* yh   = (ushort*)(ws + OFF_YH);
    ushort* yl   = (ushort*)(ws + OFF_YL);
    float*  xfp  = ws + OFF_XFP;
    float*  xfb  = ws + OFF_XFB;
    ushort* sch  = (ushort*)(ws + OFF_SCH);
    ushort* scl  = (ushort*)(ws + OFF_SCL);
    float*  pwlw = ws + OFF_PWLW;
    float*  pwlb = ws + OFF_PWLB;
    float*  lut  = ws + OFF_XFXP;       // 8192 floats
    float*  xfxp = ws + OFF_XFP;        // [32][4096] f32, free until layer0
    float*  xfxT = ws + OFF_XFXT;

    sincos_lut_kernel<<<16, 256, 0, stream>>>(lut);
    build_tables_kernel<<<1024, 256, 0, stream>>>(lut, fth, ftl, ith, itl);
    wconv_kernel<<<81, 256, 0, stream>>>(pww, p1w, lw, lb, pwb, pwh, pwl, p1h, p1l, pwlw, pwlb);

    // layer 0 input spectrum from rank-1 lift
    dftx_kernel<<<KSPLIT_X, 256, 0, stream>>>(x, fth, ftl, xfxp);
    xfx_reduce_kernel<<<16, 256, 0, stream>>>(xfxp, xfxT);
    specmix0_kernel<<<512, 256, 0, stream>>>(xfxT, lw, lb, swr, swi, yh, yl);

    // layer 0 (no hc read) — also produces layer-1 DFT partials
    layer_kernel<1><<<dim3(KSPLIT_L, BB), 256, 0, stream>>>(
        hch, yh, yl, ith, itl, pwh, pwl, pwb, x, pwlw, pwlb, fth, ftl, xfp);

    for (int l = 1; l < NLAYER; ++l) {
        xreduce_kernel<<<1024, 256, 0, stream>>>(xfp, xfb);
        specmix_kernel<<<512, 256, 0, stream>>>(
            xfb, swr + (size_t)l * WW * WW * MODES, swi + (size_t)l * WW * WW * MODES, yh, yl);
        if (l < NLAYER - 1) {
            layer_kernel<0><<<dim3(KSPLIT_L, BB), 256, 0, stream>>>(
                hch, yh, yl, ith, itl, pwh + (size_t)l * 4096, pwl + (size_t)l * 4096,
                pwb + (size_t)l * 64, x, pwlw, pwlb, fth, ftl, xfp);
        } else {
            layer3_kernel<<<dim3(TT / 64, BB), 256, 0, stream>>>(
                hch, yh, yl, ith, itl, pwh + (size_t)l * 4096, pwl + (size_t)l * 4096,
                pwb + (size_t)l * 64, p1h, p1l, p1b, p2w, p2b, sch, scl);
        }
    }

    tok_kernel<<<dim3(OUTT / 64, KSPLIT_TOK), 256, 0, stream>>>(sch, scl, tokw, xfp);
    tok_reduce_kernel<<<1024, 256, 0, stream>>>(xfp, tokb, out);
}